// Round 4
// baseline (664.261 us; speedup 1.0000x reference)
//
#include <hip/hip_runtime.h>

#define N_NODES   50000
#define N_EDGES   1600000
#define CH        128
#define OUTC      2
#define NGRAPHS   64

#define NBUCK     391          // ceil(N_NODES / 128)
#define EPB       4096         // edges per F1 block
#define F1BLOCKS  391          // ceil(N_EDGES / EPB)
#define BCAP      5120         // max bucket size handled in LDS

#define GROWS     64           // gemm rows per block

// ---------------- CSR build ----------------

__global__ void count_k(const int* __restrict__ dst, int* __restrict__ cnt) {
    int e = blockIdx.x * 256 + threadIdx.x;
    if (e < N_EDGES) atomicAdd(&cnt[dst[e]], 1);
}

// single-block exclusive scan over cnt[N_NODES]; also dis = rsqrt(cnt+1), cursor = offsets
__global__ __launch_bounds__(1024) void scan_k(const int* __restrict__ cnt,
                                               int* __restrict__ offsets,
                                               int* __restrict__ cursor,
                                               float* __restrict__ dis) {
    __shared__ int wsum[16];
    __shared__ int wpre[16];
    __shared__ int btot;
    const int tid  = threadIdx.x;
    const int lane = tid & 63;
    const int wid  = tid >> 6;
    int running = 0;
    for (int base = 0; base < N_NODES; base += 1024) {
        int i = base + tid;
        int c = (i < N_NODES) ? cnt[i] : 0;
        int v = c;
        #pragma unroll
        for (int d = 1; d < 64; d <<= 1) {
            int o = __shfl_up(v, d, 64);
            if (lane >= d) v += o;
        }
        if (lane == 63) wsum[wid] = v;
        __syncthreads();
        if (tid < 16) {
            int s  = wsum[tid];
            int sv = s;
            #pragma unroll
            for (int d = 1; d < 16; d <<= 1) {
                int o = __shfl_up(sv, d, 16);
                if (tid >= d) sv += o;
            }
            wpre[tid] = sv - s;          // exclusive prefix of wave sums
            if (tid == 15) btot = sv;    // chunk total
        }
        __syncthreads();
        int excl = v - c + wpre[wid] + running;
        if (i < N_NODES) {
            offsets[i] = excl;
            cursor[i]  = excl;
            dis[i]     = rsqrtf((float)(c + 1));
        }
        running += btot;
        __syncthreads();   // protect wsum/btot before next chunk
    }
    if (tid == 0) offsets[N_NODES] = running;
}

// bucketCursor[b] = offsets[b*128]
__global__ __launch_bounds__(512) void bucket_init_k(const int* __restrict__ offsets,
                                                     int* __restrict__ bucketCursor) {
    int b = threadIdx.x;
    if (b < NBUCK) bucketCursor[b] = offsets[b << 7];
}

// F1: block-local histogram over dst-buckets, reserve staging space, scatter (src,dst) pairs
__global__ __launch_bounds__(256) void bucket_scatter_k(const int* __restrict__ src,
                                                        const int* __restrict__ dst,
                                                        int* __restrict__ bucketCursor,
                                                        int2* __restrict__ stage) {
    __shared__ int hist[NBUCK];
    __shared__ int cur[NBUCK];
    __shared__ int gbase[NBUCK];
    const int tid = threadIdx.x;
    const int e0  = blockIdx.x * EPB;
    const int nE  = min(EPB, N_EDGES - e0);

    for (int i = tid; i < NBUCK; i += 256) hist[i] = 0;
    __syncthreads();
    for (int i = tid; i < nE; i += 256) {
        int d = dst[e0 + i];
        atomicAdd(&hist[d >> 7], 1);
    }
    __syncthreads();
    for (int i = tid; i < NBUCK; i += 256) {
        int h = hist[i];
        gbase[i] = h ? atomicAdd(&bucketCursor[i], h) : 0;
        cur[i] = 0;
    }
    __syncthreads();
    for (int i = tid; i < nE; i += 256) {
        int d = dst[e0 + i];
        int s = src[e0 + i];
        int b = d >> 7;
        int pos = gbase[b] + atomicAdd(&cur[b], 1);
        stage[pos] = make_int2(s, d);
    }
}

// F2: per-bucket ordered fill via LDS, coalesced stream-out
__global__ __launch_bounds__(256) void bucket_fill_k(const int2* __restrict__ stage,
                                                     const int* __restrict__ offsets,
                                                     int* __restrict__ cursor,
                                                     int* __restrict__ csr) {
    __shared__ int lcur[128];
    __shared__ int loc[BCAP];
    const int tid    = threadIdx.x;
    const int first  = blockIdx.x << 7;
    const int nNodes = min(128, N_NODES - first);
    const int base   = offsets[first];
    const int bend   = offsets[first + nNodes];
    const int bsize  = bend - base;

    for (int i = tid; i < nNodes; i += 256) lcur[i] = offsets[first + i] - base;
    __syncthreads();

    if (bsize <= BCAP) {
        for (int i = tid; i < bsize; i += 256) {
            int2 sd = stage[base + i];
            int pos = atomicAdd(&lcur[sd.y - first], 1);
            loc[pos] = sd.x;
        }
        __syncthreads();
        for (int i = tid; i < bsize; i += 256) csr[base + i] = loc[i];
    } else {
        // statistically unreachable fallback: direct global scatter
        for (int i = tid; i < bsize; i += 256) {
            int2 sd = stage[base + i];
            int pos = atomicAdd(&cursor[sd.y], 1);
            csr[pos] = sd.x;
        }
    }
}

// ---------------- GEMM:  out = (h @ W) * dis[row]  ----------------
// 64 rows per block; W staged once per block in 32-k quarter tiles.
// 256 threads = 8 row-groups x 32 col-groups; thread computes 8 rows x 4 cols.
__global__ __launch_bounds__(256) void gemm_scale_k(const float* __restrict__ h,
                                                    const float* __restrict__ W,
                                                    const float* __restrict__ dis,
                                                    float* __restrict__ out) {
    __shared__ float Hl[GROWS * CH];   // 32 KB
    __shared__ float Wl[32 * CH];      // 16 KB
    const int tid = threadIdx.x;
    const int rowBase = blockIdx.x * GROWS;

    // stage 64 rows of h (2048 float4s, 8 per thread)
    #pragma unroll
    for (int i = 0; i < 8; i++) {
        int f  = tid + i * 256;        // 0..2047
        int r  = f >> 5;               // 0..63
        int c4 = (f & 31) * 4;
        int n  = rowBase + r;
        float4 v = make_float4(0.f, 0.f, 0.f, 0.f);
        if (n < N_NODES) v = *(const float4*)&h[(size_t)n * CH + c4];
        *(float4*)&Hl[r * CH + c4] = v;
    }

    const int rg = tid >> 5;           // 0..7 -> rows rg*8 .. rg*8+7
    const int cg = (tid & 31) * 4;     // cols cg .. cg+3
    float4 acc[8];
    #pragma unroll
    for (int j = 0; j < 8; j++) acc[j] = make_float4(0.f, 0.f, 0.f, 0.f);

    for (int kt = 0; kt < 4; kt++) {
        __syncthreads();   // Hl ready (kt=0) / previous compute done
        // load 32x128 W quarter (1024 float4s, 4 per thread)
        #pragma unroll
        for (int i = 0; i < 4; i++) {
            int f  = tid + i * 256;    // 0..1023
            int kr = f >> 5;           // 0..31
            int c4 = (f & 31) * 4;
            *(float4*)&Wl[kr * CH + c4] = *(const float4*)&W[(size_t)(kt * 32 + kr) * CH + c4];
        }
        __syncthreads();
        #pragma unroll 2
        for (int k = 0; k < 32; k++) {
            float4 w = *(float4*)&Wl[k * CH + cg];
            #pragma unroll
            for (int j = 0; j < 8; j++) {
                float hv = Hl[(rg * 8 + j) * CH + kt * 32 + k];
                acc[j].x += hv * w.x; acc[j].y += hv * w.y;
                acc[j].z += hv * w.z; acc[j].w += hv * w.w;
            }
        }
    }

    #pragma unroll
    for (int j = 0; j < 8; j++) {
        int n = rowBase + rg * 8 + j;
        if (n < N_NODES) {
            float s = dis[n];
            float4 o = make_float4(acc[j].x * s, acc[j].y * s, acc[j].z * s, acc[j].w * s);
            *(float4*)&out[(size_t)n * CH + cg] = o;
        }
    }
}

// ---------------- Aggregate: hnext[n] = relu(dis[n]*(sum_e hs[src_e] + hs[n]) + b) ----------------
// one wave per node; 32 lanes x float4 = full 512B row per half-wave,
// so each dwordx4 gather instruction fetches TWO edges' rows (1 KB).
// 8-deep unroll -> 16 edges per iteration, 8KB in flight per wave.
__global__ __launch_bounds__(256) void agg_k(const float* __restrict__ hs,
                                             const int* __restrict__ offsets,
                                             const int* __restrict__ csr,
                                             const float* __restrict__ dis,
                                             const float* __restrict__ bias,
                                             float* __restrict__ out) {
    const int wid  = threadIdx.x >> 6;
    const int lane = threadIdx.x & 63;
    const int n = blockIdx.x * 4 + wid;
    if (n >= N_NODES) return;
    const int half = lane >> 5;        // 0: even edge slots, 1: odd
    const int c    = (lane & 31) * 4;  // 4 channels per lane

    float4 acc = make_float4(0.f, 0.f, 0.f, 0.f);
    if (half == 0) acc = *(const float4*)&hs[(size_t)n * CH + c];   // self-loop once

    const int beg = offsets[n];
    const int end = offsets[n + 1];

    for (int e = beg; e < end; e += 16) {
        int   idx[8];
        float4 v[8];
        #pragma unroll
        for (int j = 0; j < 8; j++) {
            int t = e + 2 * j + half;
            idx[j] = (t < end) ? csr[t] : -1;
        }
        #pragma unroll
        for (int j = 0; j < 8; j++) {
            int safe = (idx[j] >= 0) ? idx[j] : n;
            v[j] = *(const float4*)&hs[(size_t)safe * CH + c];
        }
        #pragma unroll
        for (int j = 0; j < 8; j++) {
            if (idx[j] >= 0) {
                acc.x += v[j].x; acc.y += v[j].y;
                acc.z += v[j].z; acc.w += v[j].w;
            }
        }
    }

    // combine the two half-wave partial sums (channels match across halves)
    acc.x += __shfl_xor(acc.x, 32);
    acc.y += __shfl_xor(acc.y, 32);
    acc.z += __shfl_xor(acc.z, 32);
    acc.w += __shfl_xor(acc.w, 32);

    if (half == 0) {
        const float dn = dis[n];
        float4 b = *(const float4*)&bias[c];
        float4 r;
        r.x = fmaxf(dn * acc.x + b.x, 0.f);
        r.y = fmaxf(dn * acc.y + b.y, 0.f);
        r.z = fmaxf(dn * acc.z + b.z, 0.f);
        r.w = fmaxf(dn * acc.w + b.w, 0.f);
        *(float4*)&out[(size_t)n * CH + c] = r;
    }
}

// ---------------- Global mean pool (batch sorted) ----------------
__global__ __launch_bounds__(256) void pool_k(const float* __restrict__ h,
                                              const int* __restrict__ batch,
                                              float* __restrict__ gsum,
                                              float* __restrict__ gcnt) {
    const int c    = threadIdx.x & 127;
    const int half = threadIdx.x >> 7;
    const int n0   = blockIdx.x * 256 + half * 128;
    float acc = 0.f;
    float cntAcc = 0.f;
    int curg = -1;
    for (int i = 0; i < 128; i++) {
        int n = n0 + i;
        if (n >= N_NODES) break;
        int g = batch[n];
        if (g != curg) {
            if (curg >= 0) {
                atomicAdd(&gsum[curg * CH + c], acc);
                if (c == 0) atomicAdd(&gcnt[curg], cntAcc);
            }
            acc = 0.f; cntAcc = 0.f; curg = g;
        }
        acc += h[n * CH + c];
        cntAcc += 1.f;
    }
    if (curg >= 0) {
        atomicAdd(&gsum[curg * CH + c], acc);
        if (c == 0) atomicAdd(&gcnt[curg], cntAcc);
    }
}

// ---------------- Head: out[g,o] = (gsum[g]/cnt[g]) @ Wlin + blin ----------------
__global__ __launch_bounds__(128) void head_k(const float* __restrict__ gsum,
                                              const float* __restrict__ gcnt,
                                              const float* __restrict__ Wlin,
                                              const float* __restrict__ blin,
                                              float* __restrict__ out) {
    const int t = threadIdx.x;      // 0..127
    const int g = t >> 1;
    const int o = t & 1;
    float cnt = fmaxf(gcnt[g], 1.f);
    float s = 0.f;
    for (int ci = 0; ci < CH; ci++) s += gsum[g * CH + ci] * Wlin[ci * OUTC + o];
    out[g * OUTC + o] = s / cnt + blin[o];
}

// ---------------- launch ----------------

static inline size_t alignup(size_t x) { return (x + 255) & ~(size_t)255; }

extern "C" void kernel_launch(void* const* d_in, const int* in_sizes, int n_in,
                              void* d_out, int out_size, void* d_ws, size_t ws_size,
                              hipStream_t stream) {
    const float* x     = (const float*)d_in[0];
    const int*   eidx  = (const int*)d_in[1];
    const int*   batch = (const int*)d_in[2];
    const float* W0    = (const float*)d_in[3];
    const float* b0    = (const float*)d_in[4];
    const float* W1    = (const float*)d_in[5];
    const float* b1    = (const float*)d_in[6];
    const float* W2    = (const float*)d_in[7];
    const float* b2    = (const float*)d_in[8];
    const float* Wlin  = (const float*)d_in[9];
    const float* blin  = (const float*)d_in[10];
    float* out = (float*)d_out;

    const int* src = eidx;
    const int* dst = eidx + N_EDGES;

    char* p = (char*)d_ws;
    int*   cnt     = (int*)p;    p += alignup(N_NODES * 4);
    int*   offsets = (int*)p;    p += alignup((N_NODES + 1) * 4);
    int*   cursor  = (int*)p;    p += alignup(N_NODES * 4);
    float* dis     = (float*)p;  p += alignup(N_NODES * 4);
    int*   bcur    = (int*)p;    p += alignup(NBUCK * 4);
    int*   csr     = (int*)p;    p += alignup((size_t)N_EDGES * 4);
    float* bufA    = (float*)p;  p += alignup((size_t)N_NODES * CH * 4);
    float* bufB    = (float*)p;  p += alignup((size_t)N_NODES * CH * 4);
    float* gsum    = (float*)p;  p += alignup(NGRAPHS * CH * 4);
    float* gcnt    = (float*)p;  p += alignup(NGRAPHS * 4);

    int2* stage = (int2*)bufA;   // 12.8 MB staging, free until gemm0/agg0

    hipMemsetAsync(cnt, 0, N_NODES * 4, stream);
    hipMemsetAsync(gsum, 0, NGRAPHS * CH * 4, stream);
    hipMemsetAsync(gcnt, 0, NGRAPHS * 4, stream);

    const int EB = (N_EDGES + 255) / 256;
    count_k<<<EB, 256, 0, stream>>>(dst, cnt);
    scan_k<<<1, 1024, 0, stream>>>(cnt, offsets, cursor, dis);
    bucket_init_k<<<1, 512, 0, stream>>>(offsets, bcur);
    bucket_scatter_k<<<F1BLOCKS, 256, 0, stream>>>(src, dst, bcur, stage);
    bucket_fill_k<<<NBUCK, 256, 0, stream>>>(stage, offsets, cursor, csr);

    const int GB = (N_NODES + GROWS - 1) / GROWS;   // 782 gemm blocks
    const int AB = (N_NODES + 3) / 4;               // agg blocks

    // layer 0: x -> bufB -> bufA
    gemm_scale_k<<<GB, 256, 0, stream>>>(x, W0, dis, bufB);
    agg_k<<<AB, 256, 0, stream>>>(bufB, offsets, csr, dis, b0, bufA);
    // layer 1
    gemm_scale_k<<<GB, 256, 0, stream>>>(bufA, W1, dis, bufB);
    agg_k<<<AB, 256, 0, stream>>>(bufB, offsets, csr, dis, b1, bufA);
    // layer 2
    gemm_scale_k<<<GB, 256, 0, stream>>>(bufA, W2, dis, bufB);
    agg_k<<<AB, 256, 0, stream>>>(bufB, offsets, csr, dis, b2, bufA);

    const int PB = (N_NODES + 255) / 256;
    pool_k<<<PB, 256, 0, stream>>>(bufA, batch, gsum, gcnt);
    head_k<<<1, 128, 0, stream>>>(gsum, gcnt, Wlin, blin, out);
}

// Round 5
// 645.007 us; speedup vs baseline: 1.0299x; 1.0299x over previous
//
#include <hip/hip_runtime.h>

#define N_NODES   50000
#define N_EDGES   1600000
#define CH        128
#define OUTC      2
#define NGRAPHS   64

#define NBUCK     391          // ceil(N_NODES / 128)
#define EPB       4096         // edges per F1 block
#define F1BLOCKS  391          // ceil(N_EDGES / EPB)
#define BCAP      5120         // max bucket size handled in LDS

#define GR        64           // gemm rows per block

// ---------------- CSR build ----------------

__global__ void count_k(const int* __restrict__ dst, int* __restrict__ cnt) {
    int e = blockIdx.x * 256 + threadIdx.x;
    if (e < N_EDGES) atomicAdd(&cnt[dst[e]], 1);
}

// single-block exclusive scan over cnt[N_NODES]; also dis = rsqrt(cnt+1), cursor = offsets
__global__ __launch_bounds__(1024) void scan_k(const int* __restrict__ cnt,
                                               int* __restrict__ offsets,
                                               int* __restrict__ cursor,
                                               float* __restrict__ dis) {
    __shared__ int wsum[16];
    __shared__ int wpre[16];
    __shared__ int btot;
    const int tid  = threadIdx.x;
    const int lane = tid & 63;
    const int wid  = tid >> 6;
    int running = 0;
    for (int base = 0; base < N_NODES; base += 1024) {
        int i = base + tid;
        int c = (i < N_NODES) ? cnt[i] : 0;
        int v = c;
        #pragma unroll
        for (int d = 1; d < 64; d <<= 1) {
            int o = __shfl_up(v, d, 64);
            if (lane >= d) v += o;
        }
        if (lane == 63) wsum[wid] = v;
        __syncthreads();
        if (tid < 16) {
            int s  = wsum[tid];
            int sv = s;
            #pragma unroll
            for (int d = 1; d < 16; d <<= 1) {
                int o = __shfl_up(sv, d, 16);
                if (tid >= d) sv += o;
            }
            wpre[tid] = sv - s;          // exclusive prefix of wave sums
            if (tid == 15) btot = sv;    // chunk total
        }
        __syncthreads();
        int excl = v - c + wpre[wid] + running;
        if (i < N_NODES) {
            offsets[i] = excl;
            cursor[i]  = excl;
            dis[i]     = rsqrtf((float)(c + 1));
        }
        running += btot;
        __syncthreads();   // protect wsum/btot before next chunk
    }
    if (tid == 0) offsets[N_NODES] = running;
}

// bucketCursor[b] = offsets[b*128]
__global__ __launch_bounds__(512) void bucket_init_k(const int* __restrict__ offsets,
                                                     int* __restrict__ bucketCursor) {
    int b = threadIdx.x;
    if (b < NBUCK) bucketCursor[b] = offsets[b << 7];
}

// F1: block-local histogram over dst-buckets, reserve staging space, scatter (src,dst) pairs
__global__ __launch_bounds__(256) void bucket_scatter_k(const int* __restrict__ src,
                                                        const int* __restrict__ dst,
                                                        int* __restrict__ bucketCursor,
                                                        int2* __restrict__ stage) {
    __shared__ int hist[NBUCK];
    __shared__ int cur[NBUCK];
    __shared__ int gbase[NBUCK];
    const int tid = threadIdx.x;
    const int e0  = blockIdx.x * EPB;
    const int nE  = min(EPB, N_EDGES - e0);

    for (int i = tid; i < NBUCK; i += 256) hist[i] = 0;
    __syncthreads();
    for (int i = tid; i < nE; i += 256) {
        int d = dst[e0 + i];
        atomicAdd(&hist[d >> 7], 1);
    }
    __syncthreads();
    for (int i = tid; i < NBUCK; i += 256) {
        int h = hist[i];
        gbase[i] = h ? atomicAdd(&bucketCursor[i], h) : 0;
        cur[i] = 0;
    }
    __syncthreads();
    for (int i = tid; i < nE; i += 256) {
        int d = dst[e0 + i];
        int s = src[e0 + i];
        int b = d >> 7;
        int pos = gbase[b] + atomicAdd(&cur[b], 1);
        stage[pos] = make_int2(s, d);
    }
}

// F2: per-bucket ordered fill via LDS, coalesced stream-out
__global__ __launch_bounds__(256) void bucket_fill_k(const int2* __restrict__ stage,
                                                     const int* __restrict__ offsets,
                                                     int* __restrict__ cursor,
                                                     int* __restrict__ csr) {
    __shared__ int lcur[128];
    __shared__ int loc[BCAP];
    const int tid    = threadIdx.x;
    const int first  = blockIdx.x << 7;
    const int nNodes = min(128, N_NODES - first);
    const int base   = offsets[first];
    const int bend   = offsets[first + nNodes];
    const int bsize  = bend - base;

    for (int i = tid; i < nNodes; i += 256) lcur[i] = offsets[first + i] - base;
    __syncthreads();

    if (bsize <= BCAP) {
        for (int i = tid; i < bsize; i += 256) {
            int2 sd = stage[base + i];
            int pos = atomicAdd(&lcur[sd.y - first], 1);
            loc[pos] = sd.x;
        }
        __syncthreads();
        for (int i = tid; i < bsize; i += 256) csr[base + i] = loc[i];
    } else {
        // statistically unreachable fallback: direct global scatter
        for (int i = tid; i < bsize; i += 256) {
            int2 sd = stage[base + i];
            int pos = atomicAdd(&cursor[sd.y], 1);
            csr[pos] = sd.x;
        }
    }
}

// ---------------- GEMM:  out = (h @ W) * dis[row]  ----------------
// 64 rows x 128 cols per block, 128 threads; thread computes 8 rows x 8 cols.
// H staged as k-slices [64][36] (pad 4 -> conflict-free b128); W quarter [32][128].
// Inner loop: 16 b128 LDS reads per 256 FMA -> VALU-bound.
__global__ __launch_bounds__(128) void gemm_scale_k(const float* __restrict__ h,
                                                    const float* __restrict__ W,
                                                    const float* __restrict__ dis,
                                                    float* __restrict__ out) {
    __shared__ float Hl[GR][36];       // 9.2 KB
    __shared__ float Wl[32][CH];       // 16 KB
    const int tid = threadIdx.x;
    const int tx  = tid & 15;          // col group: cols tx*8 .. tx*8+7
    const int ty  = tid >> 4;          // row group: rows ty*8 .. ty*8+7
    const int rowBase = blockIdx.x * GR;

    float acc[8][8];
    #pragma unroll
    for (int j = 0; j < 8; j++)
        #pragma unroll
        for (int i = 0; i < 8; i++) acc[j][i] = 0.f;

    for (int kt = 0; kt < 4; kt++) {
        __syncthreads();   // previous compute done before overwriting tiles
        // stage H k-slice: 64 rows x 32 k (512 float4, 4 per thread)
        #pragma unroll
        for (int i = 0; i < 4; i++) {
            int f = tid + i * 128;     // 0..511
            int r = f >> 3;            // 0..63
            int q = f & 7;             // 0..7 -> k offset q*4
            int n = rowBase + r;
            float4 v = make_float4(0.f, 0.f, 0.f, 0.f);
            if (n < N_NODES) v = *(const float4*)&h[(size_t)n * CH + kt * 32 + q * 4];
            *(float4*)&Hl[r][q * 4] = v;
        }
        // stage W quarter: 32 x 128 (1024 float4, 8 per thread)
        #pragma unroll
        for (int i = 0; i < 8; i++) {
            int f  = tid + i * 128;    // 0..1023
            int kr = f >> 5;           // 0..31
            int c4 = (f & 31) * 4;
            *(float4*)&Wl[kr][c4] = *(const float4*)&W[(size_t)(kt * 32 + kr) * CH + c4];
        }
        __syncthreads();

        #pragma unroll
        for (int k4 = 0; k4 < 8; k4++) {
            float4 hreg[8];
            #pragma unroll
            for (int j = 0; j < 8; j++)
                hreg[j] = *(float4*)&Hl[ty * 8 + j][k4 * 4];
            #pragma unroll
            for (int kk = 0; kk < 4; kk++) {
                float4 w0 = *(float4*)&Wl[k4 * 4 + kk][tx * 8];
                float4 w1 = *(float4*)&Wl[k4 * 4 + kk][tx * 8 + 4];
                #pragma unroll
                for (int j = 0; j < 8; j++) {
                    float hv = ((float*)&hreg[j])[kk];
                    acc[j][0] += hv * w0.x; acc[j][1] += hv * w0.y;
                    acc[j][2] += hv * w0.z; acc[j][3] += hv * w0.w;
                    acc[j][4] += hv * w1.x; acc[j][5] += hv * w1.y;
                    acc[j][6] += hv * w1.z; acc[j][7] += hv * w1.w;
                }
            }
        }
    }

    #pragma unroll
    for (int j = 0; j < 8; j++) {
        int n = rowBase + ty * 8 + j;
        if (n < N_NODES) {
            float s = dis[n];
            float4 o0 = make_float4(acc[j][0] * s, acc[j][1] * s, acc[j][2] * s, acc[j][3] * s);
            float4 o1 = make_float4(acc[j][4] * s, acc[j][5] * s, acc[j][6] * s, acc[j][7] * s);
            *(float4*)&out[(size_t)n * CH + tx * 8]     = o0;
            *(float4*)&out[(size_t)n * CH + tx * 8 + 4] = o1;
        }
    }
}

// ---------------- Aggregate: hnext[n] = relu(dis[n]*(sum_e hs[src_e] + hs[n]) + b) ----------------
// one wave per node, lane = 2 channels; 8-deep MLP unroll over edges (round-3 form)
__global__ __launch_bounds__(256) void agg_k(const float* __restrict__ hs,
                                             const int* __restrict__ offsets,
                                             const int* __restrict__ csr,
                                             const float* __restrict__ dis,
                                             const float* __restrict__ bias,
                                             float* __restrict__ out) {
    const int wid  = threadIdx.x >> 6;
    const int lane = threadIdx.x & 63;
    const int n = blockIdx.x * 4 + wid;
    if (n >= N_NODES) return;
    const int c = lane * 2;

    float ax[8], ay[8];
    #pragma unroll
    for (int j = 0; j < 8; j++) { ax[j] = 0.f; ay[j] = 0.f; }

    // self-loop term
    {
        float2 v = *(const float2*)&hs[(size_t)n * CH + c];
        ax[0] = v.x; ay[0] = v.y;
    }

    const int beg = offsets[n];
    const int end = offsets[n + 1];
    int e = beg;
    for (; e + 8 <= end; e += 8) {
        int idx[8];
        #pragma unroll
        for (int j = 0; j < 8; j++) idx[j] = csr[e + j];
        #pragma unroll
        for (int j = 0; j < 8; j++) {
            float2 v = *(const float2*)&hs[(size_t)idx[j] * CH + c];
            ax[j] += v.x; ay[j] += v.y;
        }
    }
    // tail (<= 7 edges)
    for (; e < end; e++) {
        int s = csr[e];
        float2 v = *(const float2*)&hs[(size_t)s * CH + c];
        ax[0] += v.x; ay[0] += v.y;
    }

    // pairwise combine
    #pragma unroll
    for (int j = 0; j < 4; j++) { ax[j] += ax[j + 4]; ay[j] += ay[j + 4]; }
    #pragma unroll
    for (int j = 0; j < 2; j++) { ax[j] += ax[j + 2]; ay[j] += ay[j + 2]; }
    float sx = ax[0] + ax[1];
    float sy = ay[0] + ay[1];

    const float dn = dis[n];
    float2 b = *(const float2*)&bias[c];
    float2 r;
    r.x = fmaxf(dn * sx + b.x, 0.f);
    r.y = fmaxf(dn * sy + b.y, 0.f);
    *(float2*)&out[n * CH + c] = r;
}

// ---------------- Global mean pool (batch sorted) ----------------
__global__ __launch_bounds__(256) void pool_k(const float* __restrict__ h,
                                              const int* __restrict__ batch,
                                              float* __restrict__ gsum,
                                              float* __restrict__ gcnt) {
    const int c    = threadIdx.x & 127;
    const int half = threadIdx.x >> 7;
    const int n0   = blockIdx.x * 256 + half * 128;
    float acc = 0.f;
    float cntAcc = 0.f;
    int curg = -1;
    for (int i = 0; i < 128; i++) {
        int n = n0 + i;
        if (n >= N_NODES) break;
        int g = batch[n];
        if (g != curg) {
            if (curg >= 0) {
                atomicAdd(&gsum[curg * CH + c], acc);
                if (c == 0) atomicAdd(&gcnt[curg], cntAcc);
            }
            acc = 0.f; cntAcc = 0.f; curg = g;
        }
        acc += h[n * CH + c];
        cntAcc += 1.f;
    }
    if (curg >= 0) {
        atomicAdd(&gsum[curg * CH + c], acc);
        if (c == 0) atomicAdd(&gcnt[curg], cntAcc);
    }
}

// ---------------- Head: out[g,o] = (gsum[g]/cnt[g]) @ Wlin + blin ----------------
__global__ __launch_bounds__(128) void head_k(const float* __restrict__ gsum,
                                              const float* __restrict__ gcnt,
                                              const float* __restrict__ Wlin,
                                              const float* __restrict__ blin,
                                              float* __restrict__ out) {
    const int t = threadIdx.x;      // 0..127
    const int g = t >> 1;
    const int o = t & 1;
    float cnt = fmaxf(gcnt[g], 1.f);
    float s = 0.f;
    for (int ci = 0; ci < CH; ci++) s += gsum[g * CH + ci] * Wlin[ci * OUTC + o];
    out[g * OUTC + o] = s / cnt + blin[o];
}

// ---------------- launch ----------------

static inline size_t alignup(size_t x) { return (x + 255) & ~(size_t)255; }

extern "C" void kernel_launch(void* const* d_in, const int* in_sizes, int n_in,
                              void* d_out, int out_size, void* d_ws, size_t ws_size,
                              hipStream_t stream) {
    const float* x     = (const float*)d_in[0];
    const int*   eidx  = (const int*)d_in[1];
    const int*   batch = (const int*)d_in[2];
    const float* W0    = (const float*)d_in[3];
    const float* b0    = (const float*)d_in[4];
    const float* W1    = (const float*)d_in[5];
    const float* b1    = (const float*)d_in[6];
    const float* W2    = (const float*)d_in[7];
    const float* b2    = (const float*)d_in[8];
    const float* Wlin  = (const float*)d_in[9];
    const float* blin  = (const float*)d_in[10];
    float* out = (float*)d_out;

    const int* src = eidx;
    const int* dst = eidx + N_EDGES;

    char* p = (char*)d_ws;
    int*   cnt     = (int*)p;    p += alignup(N_NODES * 4);
    int*   offsets = (int*)p;    p += alignup((N_NODES + 1) * 4);
    int*   cursor  = (int*)p;    p += alignup(N_NODES * 4);
    float* dis     = (float*)p;  p += alignup(N_NODES * 4);
    int*   bcur    = (int*)p;    p += alignup(NBUCK * 4);
    int*   csr     = (int*)p;    p += alignup((size_t)N_EDGES * 4);
    float* bufA    = (float*)p;  p += alignup((size_t)N_NODES * CH * 4);
    float* bufB    = (float*)p;  p += alignup((size_t)N_NODES * CH * 4);
    float* gsum    = (float*)p;  p += alignup(NGRAPHS * CH * 4);
    float* gcnt    = (float*)p;  p += alignup(NGRAPHS * 4);

    int2* stage = (int2*)bufA;   // 12.8 MB staging, free until gemm0/agg0

    hipMemsetAsync(cnt, 0, N_NODES * 4, stream);
    hipMemsetAsync(gsum, 0, NGRAPHS * CH * 4, stream);
    hipMemsetAsync(gcnt, 0, NGRAPHS * 4, stream);

    const int EB = (N_EDGES + 255) / 256;
    count_k<<<EB, 256, 0, stream>>>(dst, cnt);
    scan_k<<<1, 1024, 0, stream>>>(cnt, offsets, cursor, dis);
    bucket_init_k<<<1, 512, 0, stream>>>(offsets, bcur);
    bucket_scatter_k<<<F1BLOCKS, 256, 0, stream>>>(src, dst, bcur, stage);
    bucket_fill_k<<<NBUCK, 256, 0, stream>>>(stage, offsets, cursor, csr);

    const int GB = (N_NODES + GR - 1) / GR;   // 782 gemm blocks
    const int AB = (N_NODES + 3) / 4;         // agg blocks

    // layer 0: x -> bufB -> bufA
    gemm_scale_k<<<GB, 128, 0, stream>>>(x, W0, dis, bufB);
    agg_k<<<AB, 256, 0, stream>>>(bufB, offsets, csr, dis, b0, bufA);
    // layer 1
    gemm_scale_k<<<GB, 128, 0, stream>>>(bufA, W1, dis, bufB);
    agg_k<<<AB, 256, 0, stream>>>(bufB, offsets, csr, dis, b1, bufA);
    // layer 2
    gemm_scale_k<<<GB, 128, 0, stream>>>(bufA, W2, dis, bufB);
    agg_k<<<AB, 256, 0, stream>>>(bufB, offsets, csr, dis, b2, bufA);

    const int PB = (N_NODES + 255) / 256;
    pool_k<<<PB, 256, 0, stream>>>(bufA, batch, gsum, gcnt);
    head_k<<<1, 128, 0, stream>>>(gsum, gcnt, Wlin, blin, out);
}

// Round 6
// 451.005 us; speedup vs baseline: 1.4728x; 1.4302x over previous
//
#include <hip/hip_runtime.h>
#include <hip/hip_fp16.h>

#define N_NODES   50000
#define N_EDGES   1600000
#define CH        128
#define OUTC      2
#define NGRAPHS   64

#define NBUCK     391          // ceil(N_NODES / 128)
#define EPB       4096         // edges per F1 block
#define F1BLOCKS  391          // ceil(N_EDGES / EPB)
#define BCAP      5120         // max bucket size handled in LDS

#define GR        64           // gemm rows per block
#define NSB       ((N_NODES + 255) / 256)   // scan blocks = 196

// ---------------- CSR build ----------------

__global__ void count_k(const int* __restrict__ dst, int* __restrict__ cnt) {
    int e = blockIdx.x * 256 + threadIdx.x;
    if (e < N_EDGES) atomicAdd(&cnt[dst[e]], 1);
}

// scan pass 1: per-256-block sums; also dis = rsqrt(cnt+1)
__global__ __launch_bounds__(256) void scan1_k(const int* __restrict__ cnt,
                                               int* __restrict__ bsum,
                                               float* __restrict__ dis) {
    const int t = threadIdx.x;
    const int i = blockIdx.x * 256 + t;
    int c = (i < N_NODES) ? cnt[i] : 0;
    if (i < N_NODES) dis[i] = rsqrtf((float)(c + 1));
    int v = c;
    #pragma unroll
    for (int d = 1; d < 64; d <<= 1) v += __shfl_xor(v, d, 64);
    __shared__ int ws[4];
    if ((t & 63) == 0) ws[t >> 6] = v;
    __syncthreads();
    if (t == 0) bsum[blockIdx.x] = ws[0] + ws[1] + ws[2] + ws[3];
}

// scan pass 2: single small block scans the 196 block sums (exclusive)
__global__ __launch_bounds__(256) void scan2_k(const int* __restrict__ bsum,
                                               int* __restrict__ bpre,
                                               int* __restrict__ offsetsN) {
    const int t = threadIdx.x;
    const int lane = t & 63, w = t >> 6;
    int v = (t < NSB) ? bsum[t] : 0;
    int iv = v;
    #pragma unroll
    for (int d = 1; d < 64; d <<= 1) {
        int o = __shfl_up(iv, d, 64);
        if (lane >= d) iv += o;
    }
    __shared__ int wsum[4];
    if (lane == 63) wsum[w] = iv;
    __syncthreads();
    int add = 0;
    #pragma unroll
    for (int k = 0; k < 4; k++) if (k < w) add += wsum[k];
    int incl = iv + add;
    if (t < NSB) bpre[t] = incl - v;
    if (t == NSB - 1) *offsetsN = incl;      // offsets[N_NODES] = total
}

// scan pass 3: block-local exclusive scan + block prefix -> offsets & cursor
__global__ __launch_bounds__(256) void scan3_k(const int* __restrict__ cnt,
                                               const int* __restrict__ bpre,
                                               int* __restrict__ offsets,
                                               int* __restrict__ cursor) {
    const int t = threadIdx.x;
    const int i = blockIdx.x * 256 + t;
    const int lane = t & 63, w = t >> 6;
    int c = (i < N_NODES) ? cnt[i] : 0;
    int iv = c;
    #pragma unroll
    for (int d = 1; d < 64; d <<= 1) {
        int o = __shfl_up(iv, d, 64);
        if (lane >= d) iv += o;
    }
    __shared__ int wsum[4];
    if (lane == 63) wsum[w] = iv;
    __syncthreads();
    int add = bpre[blockIdx.x];
    #pragma unroll
    for (int k = 0; k < 4; k++) if (k < w) add += wsum[k];
    int excl = add + iv - c;
    if (i < N_NODES) { offsets[i] = excl; cursor[i] = excl; }
}

// bucketCursor[b] = offsets[b*128]
__global__ __launch_bounds__(512) void bucket_init_k(const int* __restrict__ offsets,
                                                     int* __restrict__ bucketCursor) {
    int b = threadIdx.x;
    if (b < NBUCK) bucketCursor[b] = offsets[b << 7];
}

// F1: block-local histogram over dst-buckets, reserve staging space, scatter (src,dst) pairs
__global__ __launch_bounds__(256) void bucket_scatter_k(const int* __restrict__ src,
                                                        const int* __restrict__ dst,
                                                        int* __restrict__ bucketCursor,
                                                        int2* __restrict__ stage) {
    __shared__ int hist[NBUCK];
    __shared__ int cur[NBUCK];
    __shared__ int gbase[NBUCK];
    const int tid = threadIdx.x;
    const int e0  = blockIdx.x * EPB;
    const int nE  = min(EPB, N_EDGES - e0);

    for (int i = tid; i < NBUCK; i += 256) hist[i] = 0;
    __syncthreads();
    for (int i = tid; i < nE; i += 256) {
        int d = dst[e0 + i];
        atomicAdd(&hist[d >> 7], 1);
    }
    __syncthreads();
    for (int i = tid; i < NBUCK; i += 256) {
        int h = hist[i];
        gbase[i] = h ? atomicAdd(&bucketCursor[i], h) : 0;
        cur[i] = 0;
    }
    __syncthreads();
    for (int i = tid; i < nE; i += 256) {
        int d = dst[e0 + i];
        int s = src[e0 + i];
        int b = d >> 7;
        int pos = gbase[b] + atomicAdd(&cur[b], 1);
        stage[pos] = make_int2(s, d);
    }
}

// F2: per-bucket ordered fill via LDS, coalesced stream-out
__global__ __launch_bounds__(256) void bucket_fill_k(const int2* __restrict__ stage,
                                                     const int* __restrict__ offsets,
                                                     int* __restrict__ cursor,
                                                     int* __restrict__ csr) {
    __shared__ int lcur[128];
    __shared__ int loc[BCAP];
    const int tid    = threadIdx.x;
    const int first  = blockIdx.x << 7;
    const int nNodes = min(128, N_NODES - first);
    const int base   = offsets[first];
    const int bend   = offsets[first + nNodes];
    const int bsize  = bend - base;

    for (int i = tid; i < nNodes; i += 256) lcur[i] = offsets[first + i] - base;
    __syncthreads();

    if (bsize <= BCAP) {
        for (int i = tid; i < bsize; i += 256) {
            int2 sd = stage[base + i];
            int pos = atomicAdd(&lcur[sd.y - first], 1);
            loc[pos] = sd.x;
        }
        __syncthreads();
        for (int i = tid; i < bsize; i += 256) csr[base + i] = loc[i];
    } else {
        // statistically unreachable fallback: direct global scatter
        for (int i = tid; i < bsize; i += 256) {
            int2 sd = stage[base + i];
            int pos = atomicAdd(&cursor[sd.y], 1);
            csr[pos] = sd.x;
        }
    }
}

// ---------------- GEMM:  hs = (h @ W) * dis[row], stored as fp16 ----------------
// 64 rows x 128 cols per block, 128 threads; thread computes 8 rows x 8 cols.
struct alignas(16) H8 { __half2 a, b, c, d; };

__global__ __launch_bounds__(128) void gemm_scale_k(const float* __restrict__ h,
                                                    const float* __restrict__ W,
                                                    const float* __restrict__ dis,
                                                    __half* __restrict__ out) {
    __shared__ float Hl[GR][36];       // 9.2 KB (pad 4 -> conflict-free b128)
    __shared__ float Wl[32][CH];       // 16 KB
    const int tid = threadIdx.x;
    const int tx  = tid & 15;          // col group: cols tx*8 .. tx*8+7
    const int ty  = tid >> 4;          // row group: rows ty*8 .. ty*8+7
    const int rowBase = blockIdx.x * GR;

    float acc[8][8];
    #pragma unroll
    for (int j = 0; j < 8; j++)
        #pragma unroll
        for (int i = 0; i < 8; i++) acc[j][i] = 0.f;

    for (int kt = 0; kt < 4; kt++) {
        __syncthreads();
        #pragma unroll
        for (int i = 0; i < 4; i++) {
            int f = tid + i * 128;     // 0..511
            int r = f >> 3;            // 0..63
            int q = f & 7;             // k offset q*4
            int n = rowBase + r;
            float4 v = make_float4(0.f, 0.f, 0.f, 0.f);
            if (n < N_NODES) v = *(const float4*)&h[(size_t)n * CH + kt * 32 + q * 4];
            *(float4*)&Hl[r][q * 4] = v;
        }
        #pragma unroll
        for (int i = 0; i < 8; i++) {
            int f  = tid + i * 128;    // 0..1023
            int kr = f >> 5;           // 0..31
            int c4 = (f & 31) * 4;
            *(float4*)&Wl[kr][c4] = *(const float4*)&W[(size_t)(kt * 32 + kr) * CH + c4];
        }
        __syncthreads();

        #pragma unroll
        for (int k4 = 0; k4 < 8; k4++) {
            float4 hreg[8];
            #pragma unroll
            for (int j = 0; j < 8; j++)
                hreg[j] = *(float4*)&Hl[ty * 8 + j][k4 * 4];
            #pragma unroll
            for (int kk = 0; kk < 4; kk++) {
                float4 w0 = *(float4*)&Wl[k4 * 4 + kk][tx * 8];
                float4 w1 = *(float4*)&Wl[k4 * 4 + kk][tx * 8 + 4];
                #pragma unroll
                for (int j = 0; j < 8; j++) {
                    float hv = ((float*)&hreg[j])[kk];
                    acc[j][0] += hv * w0.x; acc[j][1] += hv * w0.y;
                    acc[j][2] += hv * w0.z; acc[j][3] += hv * w0.w;
                    acc[j][4] += hv * w1.x; acc[j][5] += hv * w1.y;
                    acc[j][6] += hv * w1.z; acc[j][7] += hv * w1.w;
                }
            }
        }
    }

    #pragma unroll
    for (int j = 0; j < 8; j++) {
        int n = rowBase + ty * 8 + j;
        if (n < N_NODES) {
            float s = dis[n];
            H8 o;
            o.a = __floats2half2_rn(acc[j][0] * s, acc[j][1] * s);
            o.b = __floats2half2_rn(acc[j][2] * s, acc[j][3] * s);
            o.c = __floats2half2_rn(acc[j][4] * s, acc[j][5] * s);
            o.d = __floats2half2_rn(acc[j][6] * s, acc[j][7] * s);
            *(H8*)&out[(size_t)n * CH + tx * 8] = o;
        }
    }
}

// ---------------- Aggregate: h[n] = relu(dis[n]*(sum_e hs[src_e] + hs[n]) + b) ----------------
// hs is fp16 (rows 256B); one wave per node, lane = one half2 (2 channels);
// 8-deep MLP unroll, f32 accumulation.
__global__ __launch_bounds__(256) void agg_k(const __half* __restrict__ hs,
                                             const int* __restrict__ offsets,
                                             const int* __restrict__ csr,
                                             const float* __restrict__ dis,
                                             const float* __restrict__ bias,
                                             float* __restrict__ out) {
    const __half2* hs2 = (const __half2*)hs;
    const int wid  = threadIdx.x >> 6;
    const int lane = threadIdx.x & 63;
    const int n = blockIdx.x * 4 + wid;
    if (n >= N_NODES) return;

    float ax[8], ay[8];
    #pragma unroll
    for (int j = 0; j < 8; j++) { ax[j] = 0.f; ay[j] = 0.f; }

    // self-loop term
    {
        float2 v = __half22float2(hs2[(size_t)n * 64 + lane]);
        ax[0] = v.x; ay[0] = v.y;
    }

    const int beg = offsets[n];
    const int end = offsets[n + 1];
    int e = beg;
    for (; e + 8 <= end; e += 8) {
        int idx[8];
        #pragma unroll
        for (int j = 0; j < 8; j++) idx[j] = csr[e + j];
        __half2 v[8];
        #pragma unroll
        for (int j = 0; j < 8; j++) v[j] = hs2[(size_t)idx[j] * 64 + lane];
        #pragma unroll
        for (int j = 0; j < 8; j++) {
            float2 f = __half22float2(v[j]);
            ax[j] += f.x; ay[j] += f.y;
        }
    }
    for (; e < end; e++) {
        int s = csr[e];
        float2 f = __half22float2(hs2[(size_t)s * 64 + lane]);
        ax[0] += f.x; ay[0] += f.y;
    }

    #pragma unroll
    for (int j = 0; j < 4; j++) { ax[j] += ax[j + 4]; ay[j] += ay[j + 4]; }
    #pragma unroll
    for (int j = 0; j < 2; j++) { ax[j] += ax[j + 2]; ay[j] += ay[j + 2]; }
    float sx = ax[0] + ax[1];
    float sy = ay[0] + ay[1];

    const float dn = dis[n];
    float2 b = *(const float2*)&bias[lane * 2];
    float2 r;
    r.x = fmaxf(dn * sx + b.x, 0.f);
    r.y = fmaxf(dn * sy + b.y, 0.f);
    *(float2*)&out[(size_t)n * CH + lane * 2] = r;
}

// ---------------- Global mean pool (batch sorted) ----------------
__global__ __launch_bounds__(256) void pool_k(const float* __restrict__ h,
                                              const int* __restrict__ batch,
                                              float* __restrict__ gsum,
                                              float* __restrict__ gcnt) {
    const int c    = threadIdx.x & 127;
    const int half = threadIdx.x >> 7;
    const int n0   = blockIdx.x * 256 + half * 128;
    float acc = 0.f;
    float cntAcc = 0.f;
    int curg = -1;
    for (int i = 0; i < 128; i++) {
        int n = n0 + i;
        if (n >= N_NODES) break;
        int g = batch[n];
        if (g != curg) {
            if (curg >= 0) {
                atomicAdd(&gsum[curg * CH + c], acc);
                if (c == 0) atomicAdd(&gcnt[curg], cntAcc);
            }
            acc = 0.f; cntAcc = 0.f; curg = g;
        }
        acc += h[n * CH + c];
        cntAcc += 1.f;
    }
    if (curg >= 0) {
        atomicAdd(&gsum[curg * CH + c], acc);
        if (c == 0) atomicAdd(&gcnt[curg], cntAcc);
    }
}

// ---------------- Head: out[g,o] = (gsum[g]/cnt[g]) @ Wlin + blin ----------------
__global__ __launch_bounds__(128) void head_k(const float* __restrict__ gsum,
                                              const float* __restrict__ gcnt,
                                              const float* __restrict__ Wlin,
                                              const float* __restrict__ blin,
                                              float* __restrict__ out) {
    const int t = threadIdx.x;      // 0..127
    const int g = t >> 1;
    const int o = t & 1;
    float cnt = fmaxf(gcnt[g], 1.f);
    float s = 0.f;
    for (int ci = 0; ci < CH; ci++) s += gsum[g * CH + ci] * Wlin[ci * OUTC + o];
    out[g * OUTC + o] = s / cnt + blin[o];
}

// ---------------- launch ----------------

static inline size_t alignup(size_t x) { return (x + 255) & ~(size_t)255; }

extern "C" void kernel_launch(void* const* d_in, const int* in_sizes, int n_in,
                              void* d_out, int out_size, void* d_ws, size_t ws_size,
                              hipStream_t stream) {
    const float* x     = (const float*)d_in[0];
    const int*   eidx  = (const int*)d_in[1];
    const int*   batch = (const int*)d_in[2];
    const float* W0    = (const float*)d_in[3];
    const float* b0    = (const float*)d_in[4];
    const float* W1    = (const float*)d_in[5];
    const float* b1    = (const float*)d_in[6];
    const float* W2    = (const float*)d_in[7];
    const float* b2    = (const float*)d_in[8];
    const float* Wlin  = (const float*)d_in[9];
    const float* blin  = (const float*)d_in[10];
    float* out = (float*)d_out;

    const int* src = eidx;
    const int* dst = eidx + N_EDGES;

    char* p = (char*)d_ws;
    int*    cnt     = (int*)p;     p += alignup(N_NODES * 4);
    int*    offsets = (int*)p;     p += alignup((N_NODES + 1) * 4);
    int*    cursor  = (int*)p;     p += alignup(N_NODES * 4);
    float*  dis     = (float*)p;   p += alignup(N_NODES * 4);
    int*    bcur    = (int*)p;     p += alignup(NBUCK * 4);
    int*    bsum    = (int*)p;     p += alignup(NSB * 4);
    int*    bpre    = (int*)p;     p += alignup(NSB * 4);
    int*    csr     = (int*)p;     p += alignup((size_t)N_EDGES * 4);
    float*  bufA    = (float*)p;   p += alignup((size_t)N_NODES * CH * 4);
    __half* hsbuf   = (__half*)p;  p += alignup((size_t)N_NODES * CH * 2);
    float*  gsum    = (float*)p;   p += alignup(NGRAPHS * CH * 4);
    float*  gcnt    = (float*)p;   p += alignup(NGRAPHS * 4);

    int2* stage = (int2*)bufA;   // 12.8 MB staging, free until agg0 writes bufA

    hipMemsetAsync(cnt, 0, N_NODES * 4, stream);
    hipMemsetAsync(gsum, 0, NGRAPHS * CH * 4, stream);
    hipMemsetAsync(gcnt, 0, NGRAPHS * 4, stream);

    const int EB = (N_EDGES + 255) / 256;
    count_k<<<EB, 256, 0, stream>>>(dst, cnt);
    scan1_k<<<NSB, 256, 0, stream>>>(cnt, bsum, dis);
    scan2_k<<<1, 256, 0, stream>>>(bsum, bpre, &offsets[N_NODES]);
    scan3_k<<<NSB, 256, 0, stream>>>(cnt, bpre, offsets, cursor);
    bucket_init_k<<<1, 512, 0, stream>>>(offsets, bcur);
    bucket_scatter_k<<<F1BLOCKS, 256, 0, stream>>>(src, dst, bcur, stage);
    bucket_fill_k<<<NBUCK, 256, 0, stream>>>(stage, offsets, cursor, csr);

    const int GB = (N_NODES + GR - 1) / GR;   // 782 gemm blocks
    const int AB = (N_NODES + 3) / 4;         // agg blocks

    // layer 0: x -> hsbuf -> bufA
    gemm_scale_k<<<GB, 128, 0, stream>>>(x, W0, dis, hsbuf);
    agg_k<<<AB, 256, 0, stream>>>(hsbuf, offsets, csr, dis, b0, bufA);
    // layer 1
    gemm_scale_k<<<GB, 128, 0, stream>>>(bufA, W1, dis, hsbuf);
    agg_k<<<AB, 256, 0, stream>>>(hsbuf, offsets, csr, dis, b1, bufA);
    // layer 2
    gemm_scale_k<<<GB, 128, 0, stream>>>(bufA, W2, dis, hsbuf);
    agg_k<<<AB, 256, 0, stream>>>(hsbuf, offsets, csr, dis, b2, bufA);

    const int PB = (N_NODES + 255) / 256;
    pool_k<<<PB, 256, 0, stream>>>(bufA, batch, gsum, gcnt);
    head_k<<<1, 128, 0, stream>>>(gsum, gcnt, Wlin, blin, out);
}

// Round 7
// 331.090 us; speedup vs baseline: 2.0063x; 1.3622x over previous
//
#include <hip/hip_runtime.h>
#include <hip/hip_fp16.h>

#define N_NODES   50000
#define N_EDGES   1600000
#define CH        128
#define OUTC      2
#define NGRAPHS   64

#define NBUCK     391          // ceil(N_NODES / 128)
#define EPB       4096         // edges per block in edge-parallel kernels
#define F1BLOCKS  391          // ceil(N_EDGES / EPB)
#define BCAP      5120         // max bucket size handled in LDS

#define GR        64           // gemm rows per block

// ---------------- CSR build (bucket-level, no per-node atomics) ----------------

// per-bucket histogram of dst
__global__ __launch_bounds__(256) void bhist_k(const int* __restrict__ dst,
                                               int* __restrict__ bhist) {
    __shared__ int hist[NBUCK];
    const int tid = threadIdx.x;
    const int e0  = blockIdx.x * EPB;
    const int nE  = min(EPB, N_EDGES - e0);
    for (int i = tid; i < NBUCK; i += 256) hist[i] = 0;
    __syncthreads();
    for (int i = tid; i < nE; i += 256) atomicAdd(&hist[dst[e0 + i] >> 7], 1);
    __syncthreads();
    for (int i = tid; i < NBUCK; i += 256) if (hist[i]) atomicAdd(&bhist[i], hist[i]);
}

// exclusive scan of the 391 bucket totals -> bbase[392], bcur
__global__ __launch_bounds__(512) void bscan_k(const int* __restrict__ bhist,
                                               int* __restrict__ bbase,
                                               int* __restrict__ bcur) {
    const int t = threadIdx.x, lane = t & 63, w = t >> 6;
    int v = (t < NBUCK) ? bhist[t] : 0;
    int iv = v;
    #pragma unroll
    for (int d = 1; d < 64; d <<= 1) {
        int o = __shfl_up(iv, d, 64);
        if (lane >= d) iv += o;
    }
    __shared__ int ws[8];
    if (lane == 63) ws[w] = iv;
    __syncthreads();
    int add = 0;
    #pragma unroll
    for (int k = 0; k < 8; k++) if (k < w) add += ws[k];
    int excl = add + iv - v;
    if (t < NBUCK) { bbase[t] = excl; bcur[t] = excl; }
    if (t == NBUCK - 1) bbase[NBUCK] = excl + v;
}

// scatter (src,dst) pairs into bucket-contiguous staging
__global__ __launch_bounds__(256) void bucket_scatter_k(const int* __restrict__ src,
                                                        const int* __restrict__ dst,
                                                        int* __restrict__ bucketCursor,
                                                        int2* __restrict__ stage) {
    __shared__ int hist[NBUCK];
    __shared__ int cur[NBUCK];
    __shared__ int gbase[NBUCK];
    const int tid = threadIdx.x;
    const int e0  = blockIdx.x * EPB;
    const int nE  = min(EPB, N_EDGES - e0);

    for (int i = tid; i < NBUCK; i += 256) hist[i] = 0;
    __syncthreads();
    for (int i = tid; i < nE; i += 256) {
        int d = dst[e0 + i];
        atomicAdd(&hist[d >> 7], 1);
    }
    __syncthreads();
    for (int i = tid; i < NBUCK; i += 256) {
        int h = hist[i];
        gbase[i] = h ? atomicAdd(&bucketCursor[i], h) : 0;
        cur[i] = 0;
    }
    __syncthreads();
    for (int i = tid; i < nE; i += 256) {
        int d = dst[e0 + i];
        int s = src[e0 + i];
        int b = d >> 7;
        int pos = gbase[b] + atomicAdd(&cur[b], 1);
        stage[pos] = make_int2(s, d);
    }
}

// per-bucket: derive node counts/offsets/dis in LDS, order csr slice, stream out
__global__ __launch_bounds__(256) void bucket_build_k(const int2* __restrict__ stage,
                                                      const int* __restrict__ bbase,
                                                      int* __restrict__ offsets,
                                                      float* __restrict__ dis,
                                                      int* __restrict__ csr) {
    __shared__ int lcnt[128];
    __shared__ int lcur[128];
    __shared__ int wtot[2];
    __shared__ int loc[BCAP];
    const int tid    = threadIdx.x;
    const int b      = blockIdx.x;
    const int first  = b << 7;
    const int nNodes = min(128, N_NODES - first);
    const int base   = bbase[b];
    const int bsize  = bbase[b + 1] - base;

    if (tid < 128) lcnt[tid] = 0;
    __syncthreads();
    for (int i = tid; i < bsize; i += 256)
        atomicAdd(&lcnt[stage[base + i].y - first], 1);
    __syncthreads();

    // exclusive scan of lcnt[0..127] by first 128 threads
    int iv = 0, c = 0;
    if (tid < 128) {
        c = lcnt[tid];
        iv = c;
        #pragma unroll
        for (int d = 1; d < 64; d <<= 1) {
            int o = __shfl_up(iv, d, 64);
            if ((tid & 63) >= d) iv += o;
        }
        if ((tid & 63) == 63) wtot[tid >> 6] = iv;
    }
    __syncthreads();
    if (tid < 128) {
        int add  = (tid >= 64) ? wtot[0] : 0;
        int excl = add + iv - c;
        lcur[tid] = excl;
        if (tid < nNodes) {
            offsets[first + tid] = base + excl;
            dis[first + tid]     = rsqrtf((float)(c + 1));
        }
    }
    if (b == NBUCK - 1 && tid == 0) offsets[N_NODES] = base + bsize;
    __syncthreads();

    if (bsize <= BCAP) {
        for (int i = tid; i < bsize; i += 256) {
            int2 sd = stage[base + i];
            int pos = atomicAdd(&lcur[sd.y - first], 1);
            loc[pos] = sd.x;
        }
        __syncthreads();
        for (int i = tid; i < bsize; i += 256) csr[base + i] = loc[i];
    } else {
        // statistically unreachable fallback: direct global scatter
        for (int i = tid; i < bsize; i += 256) {
            int2 sd = stage[base + i];
            int pos = atomicAdd(&lcur[sd.y - first], 1);
            csr[base + pos] = sd.x;
        }
    }
}

// ---------------- graph ranges from sorted batch ----------------
__global__ __launch_bounds__(256) void boundary_k(const int* __restrict__ batch,
                                                  int* __restrict__ gstart) {
    int i = blockIdx.x * 256 + threadIdx.x;
    if (i >= N_NODES) return;
    int bc = batch[i];
    if (i == 0) {
        for (int g = 0; g <= bc; g++) gstart[g] = 0;
    } else {
        int bp = batch[i - 1];
        for (int g = bp + 1; g <= bc; g++) gstart[g] = i;
    }
    if (i == N_NODES - 1) {
        for (int g = bc + 1; g <= NGRAPHS; g++) gstart[g] = N_NODES;
    }
}

// ---------------- GEMM:  hs = (h @ W) * dis[row], stored as fp16 ----------------
struct alignas(16) H8 { __half2 a, b, c, d; };

__global__ __launch_bounds__(128) void gemm_scale_k(const float* __restrict__ h,
                                                    const float* __restrict__ W,
                                                    const float* __restrict__ dis,
                                                    __half* __restrict__ out) {
    __shared__ float Hl[GR][36];       // 9.2 KB (pad 4 -> conflict-free b128)
    __shared__ float Wl[32][CH];       // 16 KB
    const int tid = threadIdx.x;
    const int tx  = tid & 15;          // col group: cols tx*8 .. tx*8+7
    const int ty  = tid >> 4;          // row group: rows ty*8 .. ty*8+7
    const int rowBase = blockIdx.x * GR;

    float acc[8][8];
    #pragma unroll
    for (int j = 0; j < 8; j++)
        #pragma unroll
        for (int i = 0; i < 8; i++) acc[j][i] = 0.f;

    for (int kt = 0; kt < 4; kt++) {
        __syncthreads();
        #pragma unroll
        for (int i = 0; i < 4; i++) {
            int f = tid + i * 128;     // 0..511
            int r = f >> 3;            // 0..63
            int q = f & 7;             // k offset q*4
            int n = rowBase + r;
            float4 v = make_float4(0.f, 0.f, 0.f, 0.f);
            if (n < N_NODES) v = *(const float4*)&h[(size_t)n * CH + kt * 32 + q * 4];
            *(float4*)&Hl[r][q * 4] = v;
        }
        #pragma unroll
        for (int i = 0; i < 8; i++) {
            int f  = tid + i * 128;    // 0..1023
            int kr = f >> 5;           // 0..31
            int c4 = (f & 31) * 4;
            *(float4*)&Wl[kr][c4] = *(const float4*)&W[(size_t)(kt * 32 + kr) * CH + c4];
        }
        __syncthreads();

        #pragma unroll
        for (int k4 = 0; k4 < 8; k4++) {
            float4 hreg[8];
            #pragma unroll
            for (int j = 0; j < 8; j++)
                hreg[j] = *(float4*)&Hl[ty * 8 + j][k4 * 4];
            #pragma unroll
            for (int kk = 0; kk < 4; kk++) {
                float4 w0 = *(float4*)&Wl[k4 * 4 + kk][tx * 8];
                float4 w1 = *(float4*)&Wl[k4 * 4 + kk][tx * 8 + 4];
                #pragma unroll
                for (int j = 0; j < 8; j++) {
                    float hv = ((float*)&hreg[j])[kk];
                    acc[j][0] += hv * w0.x; acc[j][1] += hv * w0.y;
                    acc[j][2] += hv * w0.z; acc[j][3] += hv * w0.w;
                    acc[j][4] += hv * w1.x; acc[j][5] += hv * w1.y;
                    acc[j][6] += hv * w1.z; acc[j][7] += hv * w1.w;
                }
            }
        }
    }

    #pragma unroll
    for (int j = 0; j < 8; j++) {
        int n = rowBase + ty * 8 + j;
        if (n < N_NODES) {
            float s = dis[n];
            H8 o;
            o.a = __floats2half2_rn(acc[j][0] * s, acc[j][1] * s);
            o.b = __floats2half2_rn(acc[j][2] * s, acc[j][3] * s);
            o.c = __floats2half2_rn(acc[j][4] * s, acc[j][5] * s);
            o.d = __floats2half2_rn(acc[j][6] * s, acc[j][7] * s);
            *(H8*)&out[(size_t)n * CH + tx * 8] = o;
        }
    }
}

// ---------------- Aggregate: h[n] = relu(dis[n]*(sum_e hs[src_e] + hs[n]) + b) ----------------
__global__ __launch_bounds__(256) void agg_k(const __half* __restrict__ hs,
                                             const int* __restrict__ offsets,
                                             const int* __restrict__ csr,
                                             const float* __restrict__ dis,
                                             const float* __restrict__ bias,
                                             float* __restrict__ out) {
    const __half2* hs2 = (const __half2*)hs;
    const int wid  = threadIdx.x >> 6;
    const int lane = threadIdx.x & 63;
    const int n = blockIdx.x * 4 + wid;
    if (n >= N_NODES) return;

    float ax[8], ay[8];
    #pragma unroll
    for (int j = 0; j < 8; j++) { ax[j] = 0.f; ay[j] = 0.f; }

    {
        float2 v = __half22float2(hs2[(size_t)n * 64 + lane]);
        ax[0] = v.x; ay[0] = v.y;
    }

    const int beg = offsets[n];
    const int end = offsets[n + 1];
    int e = beg;
    for (; e + 8 <= end; e += 8) {
        int idx[8];
        #pragma unroll
        for (int j = 0; j < 8; j++) idx[j] = csr[e + j];
        __half2 v[8];
        #pragma unroll
        for (int j = 0; j < 8; j++) v[j] = hs2[(size_t)idx[j] * 64 + lane];
        #pragma unroll
        for (int j = 0; j < 8; j++) {
            float2 f = __half22float2(v[j]);
            ax[j] += f.x; ay[j] += f.y;
        }
    }
    for (; e < end; e++) {
        int s = csr[e];
        float2 f = __half22float2(hs2[(size_t)s * 64 + lane]);
        ax[0] += f.x; ay[0] += f.y;
    }

    #pragma unroll
    for (int j = 0; j < 4; j++) { ax[j] += ax[j + 4]; ay[j] += ay[j + 4]; }
    #pragma unroll
    for (int j = 0; j < 2; j++) { ax[j] += ax[j + 2]; ay[j] += ay[j + 2]; }
    float sx = ax[0] + ax[1];
    float sy = ay[0] + ay[1];

    const float dn = dis[n];
    float2 b = *(const float2*)&bias[lane * 2];
    float2 r;
    r.x = fmaxf(dn * sx + b.x, 0.f);
    r.y = fmaxf(dn * sy + b.y, 0.f);
    *(float2*)&out[(size_t)n * CH + lane * 2] = r;
}

// ---------------- Global mean pool: grid (8 chunks, 64 graphs) ----------------
__global__ __launch_bounds__(256) void pool_k(const float* __restrict__ h,
                                              const int* __restrict__ gstart,
                                              float* __restrict__ gsum) {
    const int g   = blockIdx.y;
    const int s   = blockIdx.x;        // chunk 0..7
    const int tid = threadIdx.x;
    const int r   = tid >> 5;          // 0..7 row slot
    const int cq  = tid & 31;          // channel quad
    const int start = gstart[g], end = gstart[g + 1];
    const int len   = end - start;
    const int chunk = (len + 7) >> 3;
    const int lo = start + s * chunk;
    const int hi = min(lo + chunk, end);

    float4 acc = make_float4(0.f, 0.f, 0.f, 0.f);
    for (int row = lo + r; row < hi; row += 8) {
        float4 v = *(const float4*)&h[(size_t)row * CH + cq * 4];
        acc.x += v.x; acc.y += v.y; acc.z += v.z; acc.w += v.w;
    }

    __shared__ float4 red[256];
    red[tid] = acc;
    __syncthreads();
    #pragma unroll
    for (int off = 4; off >= 1; off >>= 1) {
        if (r < off) {
            float4 o = red[tid + off * 32];
            red[tid].x += o.x; red[tid].y += o.y;
            red[tid].z += o.z; red[tid].w += o.w;
        }
        __syncthreads();
    }
    if (r == 0) {
        float4 v = red[tid];
        atomicAdd(&gsum[g * CH + cq * 4 + 0], v.x);
        atomicAdd(&gsum[g * CH + cq * 4 + 1], v.y);
        atomicAdd(&gsum[g * CH + cq * 4 + 2], v.z);
        atomicAdd(&gsum[g * CH + cq * 4 + 3], v.w);
    }
}

// ---------------- Head: out[g,o] = (gsum[g]/cnt[g]) @ Wlin + blin ----------------
__global__ __launch_bounds__(128) void head_k(const float* __restrict__ gsum,
                                              const int* __restrict__ gstart,
                                              const float* __restrict__ Wlin,
                                              const float* __restrict__ blin,
                                              float* __restrict__ out) {
    const int t = threadIdx.x;      // 0..127
    const int g = t >> 1;
    const int o = t & 1;
    float cnt = (float)max(gstart[g + 1] - gstart[g], 1);
    float s = 0.f;
    for (int ci = 0; ci < CH; ci++) s += gsum[g * CH + ci] * Wlin[ci * OUTC + o];
    out[g * OUTC + o] = s / cnt + blin[o];
}

// ---------------- launch ----------------

static inline size_t alignup(size_t x) { return (x + 255) & ~(size_t)255; }

extern "C" void kernel_launch(void* const* d_in, const int* in_sizes, int n_in,
                              void* d_out, int out_size, void* d_ws, size_t ws_size,
                              hipStream_t stream) {
    const float* x     = (const float*)d_in[0];
    const int*   eidx  = (const int*)d_in[1];
    const int*   batch = (const int*)d_in[2];
    const float* W0    = (const float*)d_in[3];
    const float* b0    = (const float*)d_in[4];
    const float* W1    = (const float*)d_in[5];
    const float* b1    = (const float*)d_in[6];
    const float* W2    = (const float*)d_in[7];
    const float* b2    = (const float*)d_in[8];
    const float* Wlin  = (const float*)d_in[9];
    const float* blin  = (const float*)d_in[10];
    float* out = (float*)d_out;

    const int* src = eidx;
    const int* dst = eidx + N_EDGES;

    char* p = (char*)d_ws;
    int*    offsets = (int*)p;     p += alignup((N_NODES + 1) * 4);
    float*  dis     = (float*)p;   p += alignup(N_NODES * 4);
    int*    bhist   = (int*)p;     p += alignup(NBUCK * 4);
    int*    bbase   = (int*)p;     p += alignup((NBUCK + 1) * 4);
    int*    bcur    = (int*)p;     p += alignup(NBUCK * 4);
    int*    gstart  = (int*)p;     p += alignup((NGRAPHS + 1) * 4);
    int*    csr     = (int*)p;     p += alignup((size_t)N_EDGES * 4);
    float*  bufA    = (float*)p;   p += alignup((size_t)N_NODES * CH * 4);
    __half* hsbuf   = (__half*)p;  p += alignup((size_t)N_NODES * CH * 2);
    float*  gsum    = (float*)p;   p += alignup(NGRAPHS * CH * 4);

    int2* stage = (int2*)bufA;   // 12.8 MB staging, free until agg0 writes bufA

    hipMemsetAsync(bhist, 0, NBUCK * 4, stream);
    hipMemsetAsync(gsum, 0, NGRAPHS * CH * 4, stream);

    bhist_k<<<F1BLOCKS, 256, 0, stream>>>(dst, bhist);
    bscan_k<<<1, 512, 0, stream>>>(bhist, bbase, bcur);
    bucket_scatter_k<<<F1BLOCKS, 256, 0, stream>>>(src, dst, bcur, stage);
    bucket_build_k<<<NBUCK, 256, 0, stream>>>(stage, bbase, offsets, dis, csr);
    boundary_k<<<(N_NODES + 255) / 256, 256, 0, stream>>>(batch, gstart);

    const int GB = (N_NODES + GR - 1) / GR;   // 782 gemm blocks
    const int AB = (N_NODES + 3) / 4;         // agg blocks

    // layer 0: x -> hsbuf -> bufA
    gemm_scale_k<<<GB, 128, 0, stream>>>(x, W0, dis, hsbuf);
    agg_k<<<AB, 256, 0, stream>>>(hsbuf, offsets, csr, dis, b0, bufA);
    // layer 1
    gemm_scale_k<<<GB, 128, 0, stream>>>(bufA, W1, dis, hsbuf);
    agg_k<<<AB, 256, 0, stream>>>(hsbuf, offsets, csr, dis, b1, bufA);
    // layer 2
    gemm_scale_k<<<GB, 128, 0, stream>>>(bufA, W2, dis, hsbuf);
    agg_k<<<AB, 256, 0, stream>>>(hsbuf, offsets, csr, dis, b2, bufA);

    pool_k<<<dim3(8, NGRAPHS), 256, 0, stream>>>(bufA, gstart, gsum);
    head_k<<<1, 128, 0, stream>>>(gsum, gstart, Wlin, blin, out);
}

// Round 8
// 307.488 us; speedup vs baseline: 2.1603x; 1.0768x over previous
//
#include <hip/hip_runtime.h>
#include <hip/hip_fp16.h>

#define N_NODES   50000
#define N_EDGES   1600000
#define CH        128
#define OUTC      2
#define NGRAPHS   64

#define NBUCK     391          // ceil(N_NODES / 128)
#define EPB       4096         // edges per block in edge-parallel kernels
#define F1BLOCKS  391          // ceil(N_EDGES / EPB)
#define BCAP      5120         // max bucket size handled in LDS

#define GR        64           // gemm rows per block

using f16x8 = __attribute__((ext_vector_type(8))) _Float16;
using f32x4 = __attribute__((ext_vector_type(4))) float;

// ---------------- CSR build (bucket-level, no per-node atomics) ----------------

__global__ __launch_bounds__(256) void bhist_k(const int* __restrict__ dst,
                                               int* __restrict__ bhist) {
    __shared__ int hist[NBUCK];
    const int tid = threadIdx.x;
    const int e0  = blockIdx.x * EPB;
    const int nE  = min(EPB, N_EDGES - e0);
    for (int i = tid; i < NBUCK; i += 256) hist[i] = 0;
    __syncthreads();
    for (int i = tid; i < nE; i += 256) atomicAdd(&hist[dst[e0 + i] >> 7], 1);
    __syncthreads();
    for (int i = tid; i < NBUCK; i += 256) if (hist[i]) atomicAdd(&bhist[i], hist[i]);
}

__global__ __launch_bounds__(512) void bscan_k(const int* __restrict__ bhist,
                                               int* __restrict__ bbase,
                                               int* __restrict__ bcur) {
    const int t = threadIdx.x, lane = t & 63, w = t >> 6;
    int v = (t < NBUCK) ? bhist[t] : 0;
    int iv = v;
    #pragma unroll
    for (int d = 1; d < 64; d <<= 1) {
        int o = __shfl_up(iv, d, 64);
        if (lane >= d) iv += o;
    }
    __shared__ int ws[8];
    if (lane == 63) ws[w] = iv;
    __syncthreads();
    int add = 0;
    #pragma unroll
    for (int k = 0; k < 8; k++) if (k < w) add += ws[k];
    int excl = add + iv - v;
    if (t < NBUCK) { bbase[t] = excl; bcur[t] = excl; }
    if (t == NBUCK - 1) bbase[NBUCK] = excl + v;
}

__global__ __launch_bounds__(256) void bucket_scatter_k(const int* __restrict__ src,
                                                        const int* __restrict__ dst,
                                                        int* __restrict__ bucketCursor,
                                                        int2* __restrict__ stage) {
    __shared__ int hist[NBUCK];
    __shared__ int cur[NBUCK];
    __shared__ int gbase[NBUCK];
    const int tid = threadIdx.x;
    const int e0  = blockIdx.x * EPB;
    const int nE  = min(EPB, N_EDGES - e0);

    for (int i = tid; i < NBUCK; i += 256) hist[i] = 0;
    __syncthreads();
    for (int i = tid; i < nE; i += 256) {
        int d = dst[e0 + i];
        atomicAdd(&hist[d >> 7], 1);
    }
    __syncthreads();
    for (int i = tid; i < NBUCK; i += 256) {
        int h = hist[i];
        gbase[i] = h ? atomicAdd(&bucketCursor[i], h) : 0;
        cur[i] = 0;
    }
    __syncthreads();
    for (int i = tid; i < nE; i += 256) {
        int d = dst[e0 + i];
        int s = src[e0 + i];
        int b = d >> 7;
        int pos = gbase[b] + atomicAdd(&cur[b], 1);
        stage[pos] = make_int2(s, d);
    }
}

__global__ __launch_bounds__(256) void bucket_build_k(const int2* __restrict__ stage,
                                                      const int* __restrict__ bbase,
                                                      int* __restrict__ offsets,
                                                      float* __restrict__ dis,
                                                      int* __restrict__ csr) {
    __shared__ int lcnt[128];
    __shared__ int lcur[128];
    __shared__ int wtot[2];
    __shared__ int loc[BCAP];
    const int tid    = threadIdx.x;
    const int b      = blockIdx.x;
    const int first  = b << 7;
    const int nNodes = min(128, N_NODES - first);
    const int base   = bbase[b];
    const int bsize  = bbase[b + 1] - base;

    if (tid < 128) lcnt[tid] = 0;
    __syncthreads();
    for (int i = tid; i < bsize; i += 256)
        atomicAdd(&lcnt[stage[base + i].y - first], 1);
    __syncthreads();

    int iv = 0, c = 0;
    if (tid < 128) {
        c = lcnt[tid];
        iv = c;
        #pragma unroll
        for (int d = 1; d < 64; d <<= 1) {
            int o = __shfl_up(iv, d, 64);
            if ((tid & 63) >= d) iv += o;
        }
        if ((tid & 63) == 63) wtot[tid >> 6] = iv;
    }
    __syncthreads();
    if (tid < 128) {
        int add  = (tid >= 64) ? wtot[0] : 0;
        int excl = add + iv - c;
        lcur[tid] = excl;
        if (tid < nNodes) {
            offsets[first + tid] = base + excl;
            dis[first + tid]     = rsqrtf((float)(c + 1));
        }
    }
    if (b == NBUCK - 1 && tid == 0) offsets[N_NODES] = base + bsize;
    __syncthreads();

    if (bsize <= BCAP) {
        for (int i = tid; i < bsize; i += 256) {
            int2 sd = stage[base + i];
            int pos = atomicAdd(&lcur[sd.y - first], 1);
            loc[pos] = sd.x;
        }
        __syncthreads();
        for (int i = tid; i < bsize; i += 256) csr[base + i] = loc[i];
    } else {
        for (int i = tid; i < bsize; i += 256) {
            int2 sd = stage[base + i];
            int pos = atomicAdd(&lcur[sd.y - first], 1);
            csr[base + pos] = sd.x;
        }
    }
}

// ---------------- graph ranges from sorted batch ----------------
__global__ __launch_bounds__(256) void boundary_k(const int* __restrict__ batch,
                                                  int* __restrict__ gstart) {
    int i = blockIdx.x * 256 + threadIdx.x;
    if (i >= N_NODES) return;
    int bc = batch[i];
    if (i == 0) {
        for (int g = 0; g <= bc; g++) gstart[g] = 0;
    } else {
        int bp = batch[i - 1];
        for (int g = bp + 1; g <= bc; g++) gstart[g] = i;
    }
    if (i == N_NODES - 1) {
        for (int g = bc + 1; g <= NGRAPHS; g++) gstart[g] = N_NODES;
    }
}

// ---------------- W -> fp16 transpose: Wt[c][k] = W[k][c] ----------------
__global__ __launch_bounds__(256) void prep_w_k(const float* __restrict__ W0,
                                                const float* __restrict__ W1,
                                                const float* __restrict__ W2,
                                                __half* __restrict__ T0,
                                                __half* __restrict__ T1,
                                                __half* __restrict__ T2) {
    const float* W = (blockIdx.x == 0) ? W0 : (blockIdx.x == 1) ? W1 : W2;
    __half* Wt     = (blockIdx.x == 0) ? T0 : (blockIdx.x == 1) ? T1 : T2;
    for (int i = threadIdx.x; i < CH * CH; i += 256) {
        int k = i >> 7, c = i & 127;
        Wt[c * CH + k] = __float2half(W[i]);
    }
}

// ---------------- MFMA GEMM: hs = (h @ W) * dis[row], fp16 out ----------------
// 64 rows x 128 cols per 256-thread block (4 waves x 16 rows).
// Wt fp16 pre-transposed [c][k]; LDS rows padded to 136 halfs (2-way conflicts only).
template <bool F32IN>
__global__ __launch_bounds__(256) void gemm_mfma_k(const void* __restrict__ hin,
                                                   const __half* __restrict__ Wt,
                                                   const float* __restrict__ dis,
                                                   __half* __restrict__ out) {
    __shared__ _Float16 Hl[GR][136];    // 17.4 KB
    __shared__ _Float16 Wl[CH][136];    // 34.8 KB
    const int tid = threadIdx.x;
    const int rowBase = blockIdx.x * GR;

    // stage Wt: thread -> col c = tid>>1, half q = tid&1 (8 x 16B)
    {
        const int c = tid >> 1, q = tid & 1;
        #pragma unroll
        for (int i = 0; i < 8; i++)
            *(f16x8*)&Wl[c][q * 64 + i * 8] =
                *(const f16x8*)&Wt[c * CH + q * 64 + i * 8];
    }
    // stage H: thread -> row r = tid>>2, quarter q = tid&3 (32 halfs)
    {
        const int r = tid >> 2, q = tid & 3;
        const int n = rowBase + r;
        if constexpr (F32IN) {
            const float* h = (const float*)hin;
            #pragma unroll
            for (int i = 0; i < 8; i++) {
                float4 v = make_float4(0.f, 0.f, 0.f, 0.f);
                if (n < N_NODES) v = *(const float4*)&h[(size_t)n * CH + q * 32 + i * 4];
                *(__half2*)&Hl[r][q * 32 + i * 4]     = __floats2half2_rn(v.x, v.y);
                *(__half2*)&Hl[r][q * 32 + i * 4 + 2] = __floats2half2_rn(v.z, v.w);
            }
        } else {
            const _Float16* h = (const _Float16*)hin;
            #pragma unroll
            for (int i = 0; i < 4; i++) {
                f16x8 v = {};
                if (n < N_NODES) v = *(const f16x8*)&h[(size_t)n * CH + q * 32 + i * 8];
                *(f16x8*)&Hl[r][q * 32 + i * 8] = v;
            }
        }
    }
    __syncthreads();

    const int w = tid >> 6, lane = tid & 63;
    const int l15 = lane & 15, kg = lane >> 4;

    f32x4 acc[8];
    #pragma unroll
    for (int t = 0; t < 8; t++) acc[t] = (f32x4){0.f, 0.f, 0.f, 0.f};

    #pragma unroll
    for (int kt = 0; kt < 4; kt++) {
        f16x8 a = *(f16x8*)&Hl[w * 16 + l15][kt * 32 + kg * 8];
        #pragma unroll
        for (int t = 0; t < 8; t++) {
            f16x8 b = *(f16x8*)&Wl[t * 16 + l15][kt * 32 + kg * 8];
            acc[t] = __builtin_amdgcn_mfma_f32_16x16x32_f16(a, b, acc[t], 0, 0, 0);
        }
    }
    __syncthreads();   // all waves done reading Hl

    // write scaled C into Hl (fp16), rows are wave-private
    #pragma unroll
    for (int r = 0; r < 4; r++) {
        const int lrow = w * 16 + kg * 4 + r;
        const int n = rowBase + lrow;
        const float s = (n < N_NODES) ? dis[n] : 0.f;
        #pragma unroll
        for (int t = 0; t < 8; t++)
            Hl[lrow][t * 16 + l15] = (_Float16)(acc[t][r] * s);
    }
    __syncthreads();

    // coalesced stream-out
    {
        const int r = tid >> 2, q = tid & 3;
        const int n = rowBase + r;
        if (n < N_NODES) {
            #pragma unroll
            for (int i = 0; i < 4; i++)
                *(f16x8*)&((_Float16*)out)[(size_t)n * CH + q * 32 + i * 8] =
                    *(f16x8*)&Hl[r][q * 32 + i * 8];
        }
    }
}

// ---------------- Aggregate: h[n] = relu(dis[n]*(sum_e hs[src_e] + hs[n]) + b), fp16 out ----------------
__global__ __launch_bounds__(256) void agg_k(const __half* __restrict__ hs,
                                             const int* __restrict__ offsets,
                                             const int* __restrict__ csr,
                                             const float* __restrict__ dis,
                                             const float* __restrict__ bias,
                                             __half* __restrict__ out) {
    const __half2* hs2 = (const __half2*)hs;
    const int wid  = threadIdx.x >> 6;
    const int lane = threadIdx.x & 63;
    const int n = blockIdx.x * 4 + wid;
    if (n >= N_NODES) return;

    float ax[8], ay[8];
    #pragma unroll
    for (int j = 0; j < 8; j++) { ax[j] = 0.f; ay[j] = 0.f; }

    {
        float2 v = __half22float2(hs2[(size_t)n * 64 + lane]);
        ax[0] = v.x; ay[0] = v.y;
    }

    const int beg = offsets[n];
    const int end = offsets[n + 1];
    int e = beg;
    for (; e + 8 <= end; e += 8) {
        int idx[8];
        #pragma unroll
        for (int j = 0; j < 8; j++) idx[j] = csr[e + j];
        __half2 v[8];
        #pragma unroll
        for (int j = 0; j < 8; j++) v[j] = hs2[(size_t)idx[j] * 64 + lane];
        #pragma unroll
        for (int j = 0; j < 8; j++) {
            float2 f = __half22float2(v[j]);
            ax[j] += f.x; ay[j] += f.y;
        }
    }
    for (; e < end; e++) {
        int s = csr[e];
        float2 f = __half22float2(hs2[(size_t)s * 64 + lane]);
        ax[0] += f.x; ay[0] += f.y;
    }

    #pragma unroll
    for (int j = 0; j < 4; j++) { ax[j] += ax[j + 4]; ay[j] += ay[j + 4]; }
    #pragma unroll
    for (int j = 0; j < 2; j++) { ax[j] += ax[j + 2]; ay[j] += ay[j + 2]; }
    float sx = ax[0] + ax[1];
    float sy = ay[0] + ay[1];

    const float dn = dis[n];
    float2 b = *(const float2*)&bias[lane * 2];
    float rx = fmaxf(dn * sx + b.x, 0.f);
    float ry = fmaxf(dn * sy + b.y, 0.f);
    ((__half2*)out)[(size_t)n * 64 + lane] = __floats2half2_rn(rx, ry);
}

// ---------------- Global mean pool over fp16 h: grid (8 chunks, 64 graphs) ----------------
__global__ __launch_bounds__(256) void pool_k(const __half* __restrict__ h,
                                              const int* __restrict__ gstart,
                                              float* __restrict__ gsum) {
    const __half2* h2 = (const __half2*)h;
    const int g   = blockIdx.y;
    const int s   = blockIdx.x;        // chunk 0..7
    const int tid = threadIdx.x;
    const int r   = tid >> 5;          // 0..7 row slot
    const int cq  = tid & 31;          // channel quad
    const int start = gstart[g], end = gstart[g + 1];
    const int len   = end - start;
    const int chunk = (len + 7) >> 3;
    const int lo = start + s * chunk;
    const int hi = min(lo + chunk, end);

    float4 acc = make_float4(0.f, 0.f, 0.f, 0.f);
    for (int row = lo + r; row < hi; row += 8) {
        float2 a = __half22float2(h2[(size_t)row * 64 + cq * 2]);
        float2 b = __half22float2(h2[(size_t)row * 64 + cq * 2 + 1]);
        acc.x += a.x; acc.y += a.y; acc.z += b.x; acc.w += b.y;
    }

    __shared__ float4 red[256];
    red[tid] = acc;
    __syncthreads();
    #pragma unroll
    for (int off = 4; off >= 1; off >>= 1) {
        if (r < off) {
            float4 o = red[tid + off * 32];
            red[tid].x += o.x; red[tid].y += o.y;
            red[tid].z += o.z; red[tid].w += o.w;
        }
        __syncthreads();
    }
    if (r == 0) {
        float4 v = red[tid];
        atomicAdd(&gsum[g * CH + cq * 4 + 0], v.x);
        atomicAdd(&gsum[g * CH + cq * 4 + 1], v.y);
        atomicAdd(&gsum[g * CH + cq * 4 + 2], v.z);
        atomicAdd(&gsum[g * CH + cq * 4 + 3], v.w);
    }
}

// ---------------- Head ----------------
__global__ __launch_bounds__(128) void head_k(const float* __restrict__ gsum,
                                              const int* __restrict__ gstart,
                                              const float* __restrict__ Wlin,
                                              const float* __restrict__ blin,
                                              float* __restrict__ out) {
    const int t = threadIdx.x;      // 0..127
    const int g = t >> 1;
    const int o = t & 1;
    float cnt = (float)max(gstart[g + 1] - gstart[g], 1);
    float s = 0.f;
    for (int ci = 0; ci < CH; ci++) s += gsum[g * CH + ci] * Wlin[ci * OUTC + o];
    out[g * OUTC + o] = s / cnt + blin[o];
}

// ---------------- launch ----------------

static inline size_t alignup(size_t x) { return (x + 255) & ~(size_t)255; }

extern "C" void kernel_launch(void* const* d_in, const int* in_sizes, int n_in,
                              void* d_out, int out_size, void* d_ws, size_t ws_size,
                              hipStream_t stream) {
    const float* x     = (const float*)d_in[0];
    const int*   eidx  = (const int*)d_in[1];
    const int*   batch = (const int*)d_in[2];
    const float* W0    = (const float*)d_in[3];
    const float* b0    = (const float*)d_in[4];
    const float* W1    = (const float*)d_in[5];
    const float* b1    = (const float*)d_in[6];
    const float* W2    = (const float*)d_in[7];
    const float* b2    = (const float*)d_in[8];
    const float* Wlin  = (const float*)d_in[9];
    const float* blin  = (const float*)d_in[10];
    float* out = (float*)d_out;

    const int* src = eidx;
    const int* dst = eidx + N_EDGES;

    char* p = (char*)d_ws;
    int*    offsets = (int*)p;     p += alignup((N_NODES + 1) * 4);
    float*  dis     = (float*)p;   p += alignup(N_NODES * 4);
    int*    bhist   = (int*)p;     p += alignup(NBUCK * 4);
    int*    bbase   = (int*)p;     p += alignup((NBUCK + 1) * 4);
    int*    bcur    = (int*)p;     p += alignup(NBUCK * 4);
    int*    gstart  = (int*)p;     p += alignup((NGRAPHS + 1) * 4);
    int*    csr     = (int*)p;     p += alignup((size_t)N_EDGES * 4);
    __half* Wt0     = (__half*)p;  p += alignup(CH * CH * 2);
    __half* Wt1     = (__half*)p;  p += alignup(CH * CH * 2);
    __half* Wt2     = (__half*)p;  p += alignup(CH * CH * 2);
    __half* bufA    = (__half*)p;  p += alignup((size_t)N_NODES * CH * 2);
    __half* hsbuf   = (__half*)p;  p += alignup((size_t)N_NODES * CH * 2);
    int2*   stage   = (int2*)p;    p += alignup((size_t)N_EDGES * 8);
    float*  gsum    = (float*)p;   p += alignup(NGRAPHS * CH * 4);

    hipMemsetAsync(bhist, 0, NBUCK * 4, stream);
    hipMemsetAsync(gsum, 0, NGRAPHS * CH * 4, stream);

    bhist_k<<<F1BLOCKS, 256, 0, stream>>>(dst, bhist);
    bscan_k<<<1, 512, 0, stream>>>(bhist, bbase, bcur);
    bucket_scatter_k<<<F1BLOCKS, 256, 0, stream>>>(src, dst, bcur, stage);
    bucket_build_k<<<NBUCK, 256, 0, stream>>>(stage, bbase, offsets, dis, csr);
    boundary_k<<<(N_NODES + 255) / 256, 256, 0, stream>>>(batch, gstart);
    prep_w_k<<<3, 256, 0, stream>>>(W0, W1, W2, Wt0, Wt1, Wt2);

    const int GB = (N_NODES + GR - 1) / GR;   // 782 gemm blocks
    const int AB = (N_NODES + 3) / 4;         // agg blocks

    // layer 0: x (f32) -> hsbuf -> bufA
    gemm_mfma_k<true><<<GB, 256, 0, stream>>>(x, Wt0, dis, hsbuf);
    agg_k<<<AB, 256, 0, stream>>>(hsbuf, offsets, csr, dis, b0, bufA);
    // layer 1
    gemm_mfma_k<false><<<GB, 256, 0, stream>>>(bufA, Wt1, dis, hsbuf);
    agg_k<<<AB, 256, 0, stream>>>(hsbuf, offsets, csr, dis, b1, bufA);
    // layer 2
    gemm_mfma_k<false><<<GB, 256, 0, stream>>>(bufA, Wt2, dis, hsbuf);
    agg_k<<<AB, 256, 0, stream>>>(hsbuf, offsets, csr, dis, b2, bufA);

    pool_k<<<dim3(8, NGRAPHS), 256, 0, stream>>>(bufA, gstart, gsum);
    head_k<<<1, 128, 0, stream>>>(gsum, gstart, Wlin, blin, out);
}